// Round 1
// baseline (1104.501 us; speedup 1.0000x reference)
//
#include <hip/hip_runtime.h>
#include <math.h>

#define HIDN 128
#define EPS 1e-5f
#define ATT_SCALE 0.17677669529663687f   // 32^-0.5

// ---------------------------------------------------------------------------
// Kernel 1: LayerNorm(h; g1,be1) fused with Q/K/V projections.
// 64 rows per block, h_norm tile staged in LDS (stride 132 to dodge bank conflicts).
// ---------------------------------------------------------------------------
__global__ __launch_bounds__(256) void k_ln_qkv(
    const float* __restrict__ h, const float* __restrict__ g1, const float* __restrict__ be1,
    const float* __restrict__ Wq, const float* __restrict__ bq,
    const float* __restrict__ Wk, const float* __restrict__ bk,
    const float* __restrict__ Wv, const float* __restrict__ bv,
    float* __restrict__ Q, float* __restrict__ K, float* __restrict__ V, int n)
{
    __shared__ float hs[64][132];
    const int t = threadIdx.x;
    const int r0 = blockIdx.x * 64;

    // stage 64x128 tile (float4 loads)
    #pragma unroll
    for (int it = 0; it < 8; ++it) {
        int idx = t + it * 256;          // 0..2047 float4 slots
        int row = idx >> 5;
        int c4  = (idx & 31) << 2;
        float4 v = make_float4(0.f, 0.f, 0.f, 0.f);
        int gr = r0 + row;
        if (gr < n) v = *(const float4*)&h[gr * HIDN + c4];
        *(float4*)&hs[row][c4] = v;
    }
    __syncthreads();

    // LN stats: 4 threads per row, 32 elems each, combine via shfl_xor(1,2)
    {
        int row  = t >> 2;
        int base = (t & 3) * 32;
        float s = 0.f, s2 = 0.f;
        #pragma unroll 8
        for (int j = 0; j < 32; ++j) { float v = hs[row][base + j]; s += v; s2 += v * v; }
        s  += __shfl_xor(s, 1);  s  += __shfl_xor(s, 2);
        s2 += __shfl_xor(s2, 1); s2 += __shfl_xor(s2, 2);
        float m   = s * (1.0f / 128.0f);
        float var = s2 * (1.0f / 128.0f) - m * m;
        float rs  = rsqrtf(var + EPS);
        #pragma unroll 8
        for (int j = 0; j < 32; ++j) {
            int c = base + j;
            float v = hs[row][c];
            hs[row][c] = (v - m) * rs * g1[c] + be1[c];
        }
    }
    __syncthreads();

    const int tx = t & 31, ty = t >> 5;   // 32 x 8 thread grid; thread = 8 rows x 4 cols
    const float* Ws[3] = {Wq, Wk, Wv};
    const float* bs[3] = {bq, bk, bv};
    float* Os[3] = {Q, K, V};

    for (int w = 0; w < 3; ++w) {
        const float* __restrict__ W = Ws[w];
        float4 bias = *(const float4*)&bs[w][tx * 4];
        float4 acc[8];
        #pragma unroll
        for (int i = 0; i < 8; ++i) acc[i] = bias;

        for (int k = 0; k < 128; k += 4) {
            float4 w0 = *(const float4*)&W[(k + 0) * HIDN + tx * 4];
            float4 w1 = *(const float4*)&W[(k + 1) * HIDN + tx * 4];
            float4 w2 = *(const float4*)&W[(k + 2) * HIDN + tx * 4];
            float4 w3 = *(const float4*)&W[(k + 3) * HIDN + tx * 4];
            #pragma unroll
            for (int i = 0; i < 8; ++i) {
                float4 a = *(const float4*)&hs[ty * 8 + i][k];
                acc[i].x = fmaf(a.x, w0.x, acc[i].x); acc[i].y = fmaf(a.x, w0.y, acc[i].y);
                acc[i].z = fmaf(a.x, w0.z, acc[i].z); acc[i].w = fmaf(a.x, w0.w, acc[i].w);
                acc[i].x = fmaf(a.y, w1.x, acc[i].x); acc[i].y = fmaf(a.y, w1.y, acc[i].y);
                acc[i].z = fmaf(a.y, w1.z, acc[i].z); acc[i].w = fmaf(a.y, w1.w, acc[i].w);
                acc[i].x = fmaf(a.z, w2.x, acc[i].x); acc[i].y = fmaf(a.z, w2.y, acc[i].y);
                acc[i].z = fmaf(a.z, w2.z, acc[i].z); acc[i].w = fmaf(a.z, w2.w, acc[i].w);
                acc[i].x = fmaf(a.w, w3.x, acc[i].x); acc[i].y = fmaf(a.w, w3.y, acc[i].y);
                acc[i].z = fmaf(a.w, w3.z, acc[i].z); acc[i].w = fmaf(a.w, w3.w, acc[i].w);
            }
        }
        #pragma unroll
        for (int i = 0; i < 8; ++i) {
            int gr = r0 + ty * 8 + i;
            if (gr < n) *(float4*)&Os[w][gr * HIDN + tx * 4] = acc[i];
        }
    }
}

// ---------------------------------------------------------------------------
// CSR build: count -> scan (3 kernels) -> scatter
// ---------------------------------------------------------------------------
__global__ void k_count(const int* __restrict__ dst, int* __restrict__ cnt, int e)
{
    int i = blockIdx.x * 256 + threadIdx.x;
    if (i < e) atomicAdd(&cnt[dst[i]], 1);
}

__global__ __launch_bounds__(256) void k_scan1(const int* __restrict__ cnt,
                                               int* __restrict__ offs,
                                               int* __restrict__ bsum, int n)
{
    __shared__ int ts[256];
    const int t = threadIdx.x;
    const int base = blockIdx.x * 1024 + t * 4;
    int v[4]; int s = 0;
    #pragma unroll
    for (int j = 0; j < 4; ++j) { int idx = base + j; v[j] = (idx < n) ? cnt[idx] : 0; s += v[j]; }
    ts[t] = s;
    __syncthreads();
    for (int off = 1; off < 256; off <<= 1) {
        int x = (t >= off) ? ts[t - off] : 0;
        __syncthreads();
        ts[t] += x;
        __syncthreads();
    }
    int run = ts[t] - s;   // exclusive prefix for this thread
    #pragma unroll
    for (int j = 0; j < 4; ++j) { int idx = base + j; if (idx < n) offs[idx] = run; run += v[j]; }
    if (t == 255) bsum[blockIdx.x] = ts[255];
}

__global__ void k_scan2(const int* __restrict__ bsum, int* __restrict__ bofs, int nb)
{
    if (threadIdx.x == 0 && blockIdx.x == 0) {
        int run = 0;
        for (int i = 0; i < nb; ++i) { bofs[i] = run; run += bsum[i]; }
    }
}

__global__ void k_scan3(const int* __restrict__ bofs, int* __restrict__ offs,
                        int* __restrict__ cur, int n)
{
    int i = blockIdx.x * 256 + threadIdx.x;
    if (i < n) {
        int o = offs[i] + bofs[i >> 10];
        offs[i] = o;
        cur[i]  = o;
    }
}

__global__ void k_scatter(const int* __restrict__ src, const int* __restrict__ dst,
                          int* __restrict__ cur, int* __restrict__ csrc, int e)
{
    int i = blockIdx.x * 256 + threadIdx.x;
    if (i < e) {
        int d = dst[i];
        int pos = atomicAdd(&cur[d], 1);
        csrc[pos] = src[i];
    }
}

// ---------------------------------------------------------------------------
// Kernel 5: per-destination-node edge attention (segment softmax + aggregation).
// One wave per node. Lane l owns dims {2l, 2l+1}; head = l>>4.
// Pass A: scores + per-head max (scores stashed to scratch).
// Pass B: exp, denom, weighted V accumulation. No float atomics anywhere.
// ---------------------------------------------------------------------------
__global__ __launch_bounds__(256) void k_edge_attn(
    const float* __restrict__ Q, const float* __restrict__ K, const float* __restrict__ V,
    const int* __restrict__ offs, const int* __restrict__ cnt, const int* __restrict__ csrc,
    float* __restrict__ sc, float* __restrict__ hnew, int n)
{
    const int wid  = threadIdx.x >> 6;
    const int lane = threadIdx.x & 63;
    const int node = blockIdx.x * 4 + wid;
    if (node >= n) return;

    const int start = offs[node];
    const int deg   = cnt[node];
    const int head  = lane >> 4;

    const float2 q = *(const float2*)&Q[node * HIDN + lane * 2];

    float m = -1e30f;
    for (int i = 0; i < deg; ++i) {
        int s = csrc[start + i];
        float2 k2 = *(const float2*)&K[s * HIDN + lane * 2];
        float p = q.x * k2.x + q.y * k2.y;
        p += __shfl_xor(p, 1);
        p += __shfl_xor(p, 2);
        p += __shfl_xor(p, 4);
        p += __shfl_xor(p, 8);
        float score = p * ATT_SCALE;
        m = fmaxf(m, score);
        if ((lane & 15) == 0) sc[(start + i) * 4 + head] = score;
    }

    float denom = 0.f;
    float2 acc = make_float2(0.f, 0.f);
    for (int i = 0; i < deg; ++i) {
        int s = csrc[start + i];
        float score = sc[(start + i) * 4 + head];
        float w = __expf(score - m);
        denom += w;
        float2 v2 = *(const float2*)&V[s * HIDN + lane * 2];
        acc.x = fmaf(w, v2.x, acc.x);
        acc.y = fmaf(w, v2.y, acc.y);
    }
    float inv = (deg > 0) ? (1.0f / denom) : 0.0f;
    float2 o = make_float2(acc.x * inv, acc.y * inv);
    *(float2*)&hnew[node * HIDN + lane * 2] = o;
}

// ---------------------------------------------------------------------------
// Kernel 6: h_attn = hnew @ Wo + bo; h1 = h + h_attn; h2 = LN(h1; g2,be2).
// Row is fully inside the block -> in-register row reduction via 32-lane shfl.
// ---------------------------------------------------------------------------
__global__ __launch_bounds__(256) void k_attnout_ln(
    const float* __restrict__ hnew, const float* __restrict__ h,
    const float* __restrict__ Wo, const float* __restrict__ bo,
    const float* __restrict__ g2, const float* __restrict__ be2,
    float* __restrict__ h1, float* __restrict__ h2, int n)
{
    __shared__ float hs[64][132];
    const int t = threadIdx.x;
    const int r0 = blockIdx.x * 64;

    #pragma unroll
    for (int it = 0; it < 8; ++it) {
        int idx = t + it * 256;
        int row = idx >> 5;
        int c4  = (idx & 31) << 2;
        float4 v = make_float4(0.f, 0.f, 0.f, 0.f);
        int gr = r0 + row;
        if (gr < n) v = *(const float4*)&hnew[gr * HIDN + c4];
        *(float4*)&hs[row][c4] = v;
    }
    __syncthreads();

    const int tx = t & 31, ty = t >> 5;
    float4 bias = *(const float4*)&bo[tx * 4];
    float4 acc[8];
    #pragma unroll
    for (int i = 0; i < 8; ++i) acc[i] = bias;

    for (int k = 0; k < 128; k += 4) {
        float4 w0 = *(const float4*)&Wo[(k + 0) * HIDN + tx * 4];
        float4 w1 = *(const float4*)&Wo[(k + 1) * HIDN + tx * 4];
        float4 w2 = *(const float4*)&Wo[(k + 2) * HIDN + tx * 4];
        float4 w3 = *(const float4*)&Wo[(k + 3) * HIDN + tx * 4];
        #pragma unroll
        for (int i = 0; i < 8; ++i) {
            float4 a = *(const float4*)&hs[ty * 8 + i][k];
            acc[i].x = fmaf(a.x, w0.x, acc[i].x); acc[i].y = fmaf(a.x, w0.y, acc[i].y);
            acc[i].z = fmaf(a.x, w0.z, acc[i].z); acc[i].w = fmaf(a.x, w0.w, acc[i].w);
            acc[i].x = fmaf(a.y, w1.x, acc[i].x); acc[i].y = fmaf(a.y, w1.y, acc[i].y);
            acc[i].z = fmaf(a.y, w1.z, acc[i].z); acc[i].w = fmaf(a.y, w1.w, acc[i].w);
            acc[i].x = fmaf(a.z, w2.x, acc[i].x); acc[i].y = fmaf(a.z, w2.y, acc[i].y);
            acc[i].z = fmaf(a.z, w2.z, acc[i].z); acc[i].w = fmaf(a.z, w2.w, acc[i].w);
            acc[i].x = fmaf(a.w, w3.x, acc[i].x); acc[i].y = fmaf(a.w, w3.y, acc[i].y);
            acc[i].z = fmaf(a.w, w3.z, acc[i].z); acc[i].w = fmaf(a.w, w3.w, acc[i].w);
        }
    }

    float4 g2v  = *(const float4*)&g2[tx * 4];
    float4 be2v = *(const float4*)&be2[tx * 4];

    #pragma unroll
    for (int i = 0; i < 8; ++i) {
        int gr = r0 + ty * 8 + i;
        float4 res = make_float4(0.f, 0.f, 0.f, 0.f);
        if (gr < n) res = *(const float4*)&h[gr * HIDN + tx * 4];
        float4 a = acc[i];
        a.x += res.x; a.y += res.y; a.z += res.z; a.w += res.w;

        float s  = a.x + a.y + a.z + a.w;
        float s2 = a.x * a.x + a.y * a.y + a.z * a.z + a.w * a.w;
        #pragma unroll
        for (int msk = 1; msk < 32; msk <<= 1) {
            s  += __shfl_xor(s, msk);
            s2 += __shfl_xor(s2, msk);
        }
        float mean = s * (1.0f / 128.0f);
        float var  = s2 * (1.0f / 128.0f) - mean * mean;
        float rs   = rsqrtf(var + EPS);

        if (gr < n) {
            *(float4*)&h1[gr * HIDN + tx * 4] = a;
            float4 o;
            o.x = (a.x - mean) * rs * g2v.x + be2v.x;
            o.y = (a.y - mean) * rs * g2v.y + be2v.y;
            o.z = (a.z - mean) * rs * g2v.z + be2v.z;
            o.w = (a.w - mean) * rs * g2v.w + be2v.w;
            *(float4*)&h2[gr * HIDN + tx * 4] = o;
        }
    }
}

// ---------------------------------------------------------------------------
// Kernel 7: t = relu(h2 @ W1 + b1).  W1 is [128][256]; blockIdx.y picks col half.
// ---------------------------------------------------------------------------
__global__ __launch_bounds__(256) void k_ffn1(
    const float* __restrict__ h2, const float* __restrict__ W1, const float* __restrict__ b1,
    float* __restrict__ tbuf, int n)
{
    __shared__ float hs[64][132];
    const int t = threadIdx.x;
    const int r0 = blockIdx.x * 64;
    const int ch = blockIdx.y * 128;

    #pragma unroll
    for (int it = 0; it < 8; ++it) {
        int idx = t + it * 256;
        int row = idx >> 5;
        int c4  = (idx & 31) << 2;
        float4 v = make_float4(0.f, 0.f, 0.f, 0.f);
        int gr = r0 + row;
        if (gr < n) v = *(const float4*)&h2[gr * HIDN + c4];
        *(float4*)&hs[row][c4] = v;
    }
    __syncthreads();

    const int tx = t & 31, ty = t >> 5;
    float4 bias = *(const float4*)&b1[ch + tx * 4];
    float4 acc[8];
    #pragma unroll
    for (int i = 0; i < 8; ++i) acc[i] = bias;

    for (int k = 0; k < 128; k += 4) {
        float4 w0 = *(const float4*)&W1[(k + 0) * 256 + ch + tx * 4];
        float4 w1 = *(const float4*)&W1[(k + 1) * 256 + ch + tx * 4];
        float4 w2 = *(const float4*)&W1[(k + 2) * 256 + ch + tx * 4];
        float4 w3 = *(const float4*)&W1[(k + 3) * 256 + ch + tx * 4];
        #pragma unroll
        for (int i = 0; i < 8; ++i) {
            float4 a = *(const float4*)&hs[ty * 8 + i][k];
            acc[i].x = fmaf(a.x, w0.x, acc[i].x); acc[i].y = fmaf(a.x, w0.y, acc[i].y);
            acc[i].z = fmaf(a.x, w0.z, acc[i].z); acc[i].w = fmaf(a.x, w0.w, acc[i].w);
            acc[i].x = fmaf(a.y, w1.x, acc[i].x); acc[i].y = fmaf(a.y, w1.y, acc[i].y);
            acc[i].z = fmaf(a.y, w1.z, acc[i].z); acc[i].w = fmaf(a.y, w1.w, acc[i].w);
            acc[i].x = fmaf(a.z, w2.x, acc[i].x); acc[i].y = fmaf(a.z, w2.y, acc[i].y);
            acc[i].z = fmaf(a.z, w2.z, acc[i].z); acc[i].w = fmaf(a.z, w2.w, acc[i].w);
            acc[i].x = fmaf(a.w, w3.x, acc[i].x); acc[i].y = fmaf(a.w, w3.y, acc[i].y);
            acc[i].z = fmaf(a.w, w3.z, acc[i].z); acc[i].w = fmaf(a.w, w3.w, acc[i].w);
        }
    }

    #pragma unroll
    for (int i = 0; i < 8; ++i) {
        int gr = r0 + ty * 8 + i;
        if (gr < n) {
            float4 a = acc[i];
            a.x = fmaxf(a.x, 0.f); a.y = fmaxf(a.y, 0.f);
            a.z = fmaxf(a.z, 0.f); a.w = fmaxf(a.w, 0.f);
            *(float4*)&tbuf[gr * 256 + ch + tx * 4] = a;
        }
    }
}

// ---------------------------------------------------------------------------
// Kernel 8: out = h1 + t @ W2 + b2.  K=256 -> two 128-wide LDS chunks.
// ---------------------------------------------------------------------------
__global__ __launch_bounds__(256) void k_ffn2(
    const float* __restrict__ tbuf, const float* __restrict__ h1,
    const float* __restrict__ W2, const float* __restrict__ b2,
    float* __restrict__ out, int n)
{
    __shared__ float hs[64][132];
    const int t = threadIdx.x;
    const int r0 = blockIdx.x * 64;
    const int tx = t & 31, ty = t >> 5;

    float4 bias = *(const float4*)&b2[tx * 4];
    float4 acc[8];
    #pragma unroll
    for (int i = 0; i < 8; ++i) {
        int gr = r0 + ty * 8 + i;
        float4 res = make_float4(0.f, 0.f, 0.f, 0.f);
        if (gr < n) res = *(const float4*)&h1[gr * HIDN + tx * 4];
        acc[i] = make_float4(bias.x + res.x, bias.y + res.y, bias.z + res.z, bias.w + res.w);
    }

    for (int kc = 0; kc < 2; ++kc) {
        #pragma unroll
        for (int it = 0; it < 8; ++it) {
            int idx = t + it * 256;
            int row = idx >> 5;
            int c4  = (idx & 31) << 2;
            float4 v = make_float4(0.f, 0.f, 0.f, 0.f);
            int gr = r0 + row;
            if (gr < n) v = *(const float4*)&tbuf[gr * 256 + kc * 128 + c4];
            *(float4*)&hs[row][c4] = v;
        }
        __syncthreads();

        for (int k = 0; k < 128; k += 4) {
            int kk = kc * 128 + k;
            float4 w0 = *(const float4*)&W2[(kk + 0) * HIDN + tx * 4];
            float4 w1 = *(const float4*)&W2[(kk + 1) * HIDN + tx * 4];
            float4 w2 = *(const float4*)&W2[(kk + 2) * HIDN + tx * 4];
            float4 w3 = *(const float4*)&W2[(kk + 3) * HIDN + tx * 4];
            #pragma unroll
            for (int i = 0; i < 8; ++i) {
                float4 a = *(const float4*)&hs[ty * 8 + i][k];
                acc[i].x = fmaf(a.x, w0.x, acc[i].x); acc[i].y = fmaf(a.x, w0.y, acc[i].y);
                acc[i].z = fmaf(a.x, w0.z, acc[i].z); acc[i].w = fmaf(a.x, w0.w, acc[i].w);
                acc[i].x = fmaf(a.y, w1.x, acc[i].x); acc[i].y = fmaf(a.y, w1.y, acc[i].y);
                acc[i].z = fmaf(a.y, w1.z, acc[i].z); acc[i].w = fmaf(a.y, w1.w, acc[i].w);
                acc[i].x = fmaf(a.z, w2.x, acc[i].x); acc[i].y = fmaf(a.z, w2.y, acc[i].y);
                acc[i].z = fmaf(a.z, w2.z, acc[i].z); acc[i].w = fmaf(a.z, w2.w, acc[i].w);
                acc[i].x = fmaf(a.w, w3.x, acc[i].x); acc[i].y = fmaf(a.w, w3.y, acc[i].y);
                acc[i].z = fmaf(a.w, w3.z, acc[i].z); acc[i].w = fmaf(a.w, w3.w, acc[i].w);
            }
        }
        __syncthreads();
    }

    #pragma unroll
    for (int i = 0; i < 8; ++i) {
        int gr = r0 + ty * 8 + i;
        if (gr < n) *(float4*)&out[gr * HIDN + tx * 4] = acc[i];
    }
}

// ---------------------------------------------------------------------------
extern "C" void kernel_launch(void* const* d_in, const int* in_sizes, int n_in,
                              void* d_out, int out_size, void* d_ws, size_t ws_size,
                              hipStream_t stream)
{
    const float* h   = (const float*)d_in[0];
    const int*   src = (const int*)  d_in[1];
    const int*   dst = (const int*)  d_in[2];
    const float* Wq  = (const float*)d_in[3];
    const float* bq  = (const float*)d_in[4];
    const float* Wk  = (const float*)d_in[5];
    const float* bk  = (const float*)d_in[6];
    const float* Wv  = (const float*)d_in[7];
    const float* bv  = (const float*)d_in[8];
    const float* Wo  = (const float*)d_in[9];
    const float* bo  = (const float*)d_in[10];
    const float* W1  = (const float*)d_in[11];
    const float* b1  = (const float*)d_in[12];
    const float* W2  = (const float*)d_in[13];
    const float* b2  = (const float*)d_in[14];
    const float* g1  = (const float*)d_in[15];
    const float* be1 = (const float*)d_in[16];
    const float* g2  = (const float*)d_in[17];
    const float* be2 = (const float*)d_in[18];

    const int n = in_sizes[0] / HIDN;    // 100000
    const int e = in_sizes[1];           // 1600000
    float* out = (float*)d_out;

    // workspace layout (floats)
    const size_t NF = (size_t)n * HIDN;
    float* f     = (float*)d_ws;
    float* Q     = f;                 // NF
    float* K     = f + NF;            // NF
    float* V     = f + 2 * NF;        // NF
    float* hnew  = f + 3 * NF;        // NF
    float* sc    = f + 4 * NF;        // 4*e
    int*   ip    = (int*)(f + 4 * NF + (size_t)4 * e);
    int*   csrc  = ip;                // e
    int*   cnt   = csrc + e;          // n
    int*   offs  = cnt + n;           // n
    int*   cur   = offs + n;          // n
    int*   bsum  = cur + n;           // 256
    int*   bofs  = bsum + 256;        // 256
    // aliases (lifetimes disjoint)
    float* h1    = Q;                 // after k_edge_attn, Q is dead
    float* h2    = K;                 // after k_edge_attn, K is dead
    float* tbuf  = V;                 // spans V + hnew (2*NF floats), dead after k_attnout_ln

    const int nb = (n + 1023) / 1024;

    hipMemsetAsync(cnt, 0, (size_t)n * sizeof(int), stream);

    k_count  <<<(e + 255) / 256, 256, 0, stream>>>(dst, cnt, e);
    k_scan1  <<<nb, 256, 0, stream>>>(cnt, offs, bsum, n);
    k_scan2  <<<1, 64, 0, stream>>>(bsum, bofs, nb);
    k_scan3  <<<(n + 255) / 256, 256, 0, stream>>>(bofs, offs, cur, n);
    k_scatter<<<(e + 255) / 256, 256, 0, stream>>>(src, dst, cur, csrc, e);

    k_ln_qkv <<<(n + 63) / 64, 256, 0, stream>>>(h, g1, be1, Wq, bq, Wk, bk, Wv, bv, Q, K, V, n);

    k_edge_attn<<<(n + 3) / 4, 256, 0, stream>>>(Q, K, V, offs, cnt, csrc, sc, hnew, n);

    k_attnout_ln<<<(n + 63) / 64, 256, 0, stream>>>(hnew, h, Wo, bo, g2, be2, h1, h2, n);

    k_ffn1<<<dim3((n + 63) / 64, 2), 256, 0, stream>>>(h2, W1, b1, tbuf, n);

    k_ffn2<<<(n + 63) / 64, 256, 0, stream>>>(tbuf, h1, W2, b2, out, n);
}

// Round 5
// 588.945 us; speedup vs baseline: 1.8754x; 1.8754x over previous
//
#include <hip/hip_runtime.h>
#include <math.h>

#define HIDN 128
#define EPS 1e-5f
#define ATT_SCALE 0.17677669529663687f   // 32^-0.5

typedef unsigned int  u32;
typedef unsigned short u16;
typedef __attribute__((ext_vector_type(8))) short bf16x8;   // 8 bf16 in 4 VGPRs
typedef __attribute__((ext_vector_type(4))) float f32x4;

__device__ __forceinline__ u16 f2b(float x) {           // fp32 -> bf16 RNE
    u32 u = __float_as_uint(x);
    u += 0x7FFFu + ((u >> 16) & 1u);
    return (u16)(u >> 16);
}
__device__ __forceinline__ float b2f(u16 x) { return __uint_as_float(((u32)x) << 16); }

#define MFMA(a, b, c) __builtin_amdgcn_mfma_f32_16x16x32_bf16((a), (b), (c), 0, 0, 0)

// ---------------------------------------------------------------------------
// LN1: hn = LN(h; g1, be1) as bf16.  One wave per row.
// ---------------------------------------------------------------------------
__global__ __launch_bounds__(256) void k_ln1(
    const float* __restrict__ h, const float* __restrict__ g, const float* __restrict__ b,
    u16* __restrict__ hn, int n)
{
    const int row = blockIdx.x * 4 + (threadIdx.x >> 6);
    const int lane = threadIdx.x & 63;
    if (row >= n) return;
    float2 v = *(const float2*)&h[(size_t)row * HIDN + lane * 2];
    float s = v.x + v.y, s2 = v.x * v.x + v.y * v.y;
    #pragma unroll
    for (int m = 1; m < 64; m <<= 1) { s += __shfl_xor(s, m); s2 += __shfl_xor(s2, m); }
    float mean = s * (1.f / 128.f);
    float var  = s2 * (1.f / 128.f) - mean * mean;
    float rs   = rsqrtf(var + EPS);
    float2 gv = *(const float2*)&g[lane * 2];
    float2 bv = *(const float2*)&b[lane * 2];
    u16 o0 = f2b((v.x - mean) * rs * gv.x + bv.x);
    u16 o1 = f2b((v.y - mean) * rs * gv.y + bv.y);
    *(u32*)&hn[(size_t)row * HIDN + lane * 2] = (u32)o0 | ((u32)o1 << 16);
}

// ---------------------------------------------------------------------------
// Pack all 6 weight matrices (fp32 row-major [K][N]) into MFMA B-fragment
// order, bf16.  Fragment fi = t*KC + c; lane l; elem j  ->  W[c*32 + (l>>4)*8 + j][t*16 + (l&15)]
// Segments: Wq,Wk,Wv,Wo (128x128, 2048 thr each), W1 (128x256, 4096), W2 (256x128, 4096).
// ---------------------------------------------------------------------------
__global__ __launch_bounds__(256) void k_pack_all(
    const float* __restrict__ Wq, const float* __restrict__ Wk, const float* __restrict__ Wv,
    const float* __restrict__ Wo, const float* __restrict__ W1, const float* __restrict__ W2,
    u16* __restrict__ out)
{
    int idx = blockIdx.x * 256 + threadIdx.x;
    const float* W; int K, N, base, local;
    if      (idx <  2048) { W = Wq; K = 128; N = 128; base = 0;     local = idx; }
    else if (idx <  4096) { W = Wk; K = 128; N = 128; base = 16384; local = idx - 2048; }
    else if (idx <  6144) { W = Wv; K = 128; N = 128; base = 32768; local = idx - 4096; }
    else if (idx <  8192) { W = Wo; K = 128; N = 128; base = 49152; local = idx - 6144; }
    else if (idx < 12288) { W = W1; K = 128; N = 256; base = 65536; local = idx - 8192; }
    else if (idx < 16384) { W = W2; K = 256; N = 128; base = 98304; local = idx - 12288; }
    else return;
    const int KC = K >> 5;
    const int l  = local & 63;
    const int tc = local >> 6;
    const int c  = tc % KC;
    const int t  = tc / KC;
    const int col = l & 15, hg = l >> 4;
    const int kbase = c * 32 + hg * 8;
    u16 v[8];
    #pragma unroll
    for (int j = 0; j < 8; ++j) v[j] = f2b(W[(size_t)(kbase + j) * N + t * 16 + col]);
    uint4 o;
    o.x = (u32)v[0] | ((u32)v[1] << 16);
    o.y = (u32)v[2] | ((u32)v[3] << 16);
    o.z = (u32)v[4] | ((u32)v[5] << 16);
    o.w = (u32)v[6] | ((u32)v[7] << 16);
    *(uint4*)&out[base + local * 8] = o;
}

// ---------------------------------------------------------------------------
// QKV: Q/K/V = hn @ W{q,k,v} + b.  One wave per 16 rows; A-frags in registers.
// ---------------------------------------------------------------------------
__global__ __launch_bounds__(256) void k_qkv(
    const u16* __restrict__ hn,
    const u16* __restrict__ Bq, const u16* __restrict__ Bk, const u16* __restrict__ Bv,
    const float* __restrict__ bq, const float* __restrict__ bk, const float* __restrict__ bv,
    u16* __restrict__ Q, u16* __restrict__ K, u16* __restrict__ V, int M)
{
    const int slab = blockIdx.x * 4 + (threadIdx.x >> 6);
    const int l = threadIdx.x & 63;
    const int r0 = slab * 16;
    if (r0 >= M) return;
    const int col = l & 15, hg = l >> 4;
    const u16* ar = hn + (size_t)(r0 + col) * 128 + hg * 8;
    bf16x8 a0 = *(const bf16x8*)(ar);
    bf16x8 a1 = *(const bf16x8*)(ar + 32);
    bf16x8 a2 = *(const bf16x8*)(ar + 64);
    bf16x8 a3 = *(const bf16x8*)(ar + 96);
    const u16*  Bs[3] = {Bq, Bk, Bv};
    const float* bs[3] = {bq, bk, bv};
    u16*        Os[3] = {Q, K, V};
    #pragma unroll
    for (int w = 0; w < 3; ++w) {
        const u16* Bp = Bs[w];
        const float* bias = bs[w];
        u16* O = Os[w];
        #pragma unroll
        for (int t = 0; t < 8; ++t) {
            float bb = bias[t * 16 + col];
            f32x4 c = {bb, bb, bb, bb};
            const u16* bp = Bp + t * 2048 + l * 8;
            c = MFMA(a0, *(const bf16x8*)(bp),        c);
            c = MFMA(a1, *(const bf16x8*)(bp + 512),  c);
            c = MFMA(a2, *(const bf16x8*)(bp + 1024), c);
            c = MFMA(a3, *(const bf16x8*)(bp + 1536), c);
            #pragma unroll
            for (int r = 0; r < 4; ++r)
                O[(size_t)(r0 + hg * 4 + r) * 128 + t * 16 + col] = f2b(c[r]);
        }
    }
}

// ---------------------------------------------------------------------------
// CSR build: count -> scan (3 kernels) -> scatter
// ---------------------------------------------------------------------------
__global__ void k_count(const int* __restrict__ dst, int* __restrict__ cnt, int e)
{
    int i = blockIdx.x * 256 + threadIdx.x;
    if (i < e) atomicAdd(&cnt[dst[i]], 1);
}

__global__ __launch_bounds__(256) void k_scan1(const int* __restrict__ cnt,
                                               int* __restrict__ offs,
                                               int* __restrict__ bsum, int n)
{
    __shared__ int ts[256];
    const int t = threadIdx.x;
    const int base = blockIdx.x * 1024 + t * 4;
    int v[4]; int s = 0;
    #pragma unroll
    for (int j = 0; j < 4; ++j) { int idx = base + j; v[j] = (idx < n) ? cnt[idx] : 0; s += v[j]; }
    ts[t] = s;
    __syncthreads();
    for (int off = 1; off < 256; off <<= 1) {
        int x = (t >= off) ? ts[t - off] : 0;
        __syncthreads();
        ts[t] += x;
        __syncthreads();
    }
    int run = ts[t] - s;
    #pragma unroll
    for (int j = 0; j < 4; ++j) { int idx = base + j; if (idx < n) offs[idx] = run; run += v[j]; }
    if (t == 255) bsum[blockIdx.x] = ts[255];
}

__global__ void k_scan2(const int* __restrict__ bsum, int* __restrict__ bofs, int nb)
{
    if (threadIdx.x == 0 && blockIdx.x == 0) {
        int run = 0;
        for (int i = 0; i < nb; ++i) { bofs[i] = run; run += bsum[i]; }
    }
}

__global__ void k_scan3(const int* __restrict__ bofs, int* __restrict__ offs,
                        int* __restrict__ cur, int n)
{
    int i = blockIdx.x * 256 + threadIdx.x;
    if (i < n) {
        int o = offs[i] + bofs[i >> 10];
        offs[i] = o;
        cur[i]  = o;
    }
}

__global__ void k_scatter(const int* __restrict__ src, const int* __restrict__ dst,
                          int* __restrict__ cur, int* __restrict__ csrc, int e)
{
    int i = blockIdx.x * 256 + threadIdx.x;
    if (i < e) {
        int d = dst[i];
        int pos = atomicAdd(&cur[d], 1);
        csrc[pos] = src[i];
    }
}

// ---------------------------------------------------------------------------
// Edge attention: single pass, no max subtraction (scores are O(1) by
// construction -> exp is safe; softmax is shift-invariant so result identical).
// One wave per node; lane owns dims {2l, 2l+1}; head = lane>>4.
// 64 edge indices prefetched per coalesced load; 4-edge unroll for MLP.
// ---------------------------------------------------------------------------
__global__ __launch_bounds__(256) void k_edge(
    const u16* __restrict__ Qb, const u16* __restrict__ Kb, const u16* __restrict__ Vb,
    const int* __restrict__ offs, const int* __restrict__ cnt, const int* __restrict__ csrc,
    u16* __restrict__ hnew, int n)
{
    const int wid  = threadIdx.x >> 6;
    const int lane = threadIdx.x & 63;
    const int node = blockIdx.x * 4 + wid;
    if (node >= n) return;
    const int start = offs[node];
    const int deg   = cnt[node];

    const u32 qu = *(const u32*)&Qb[(size_t)node * 128 + lane * 2];
    const float q0 = b2f((u16)(qu & 0xFFFF));
    const float q1 = b2f((u16)(qu >> 16));

    float denom = 0.f, o0 = 0.f, o1 = 0.f;

    for (int base = 0; base < deg; base += 64) {
        int m = deg - base; if (m > 64) m = 64;
        int myidx = 0;
        if (lane < m) myidx = csrc[start + base + lane];
        int j = 0;
        for (; j + 4 <= m; j += 4) {
            int s0 = __shfl(myidx, j + 0);
            int s1 = __shfl(myidx, j + 1);
            int s2 = __shfl(myidx, j + 2);
            int s3 = __shfl(myidx, j + 3);
            const u32 k0 = *(const u32*)&Kb[(size_t)s0 * 128 + lane * 2];
            const u32 k1 = *(const u32*)&Kb[(size_t)s1 * 128 + lane * 2];
            const u32 k2 = *(const u32*)&Kb[(size_t)s2 * 128 + lane * 2];
            const u32 k3 = *(const u32*)&Kb[(size_t)s3 * 128 + lane * 2];
            const u32 v0 = *(const u32*)&Vb[(size_t)s0 * 128 + lane * 2];
            const u32 v1 = *(const u32*)&Vb[(size_t)s1 * 128 + lane * 2];
            const u32 v2 = *(const u32*)&Vb[(size_t)s2 * 128 + lane * 2];
            const u32 v3 = *(const u32*)&Vb[(size_t)s3 * 128 + lane * 2];
            float p0 = q0 * b2f((u16)(k0 & 0xFFFF)) + q1 * b2f((u16)(k0 >> 16));
            float p1 = q0 * b2f((u16)(k1 & 0xFFFF)) + q1 * b2f((u16)(k1 >> 16));
            float p2 = q0 * b2f((u16)(k2 & 0xFFFF)) + q1 * b2f((u16)(k2 >> 16));
            float p3 = q0 * b2f((u16)(k3 & 0xFFFF)) + q1 * b2f((u16)(k3 >> 16));
            p0 += __shfl_xor(p0, 1); p1 += __shfl_xor(p1, 1); p2 += __shfl_xor(p2, 1); p3 += __shfl_xor(p3, 1);
            p0 += __shfl_xor(p0, 2); p1 += __shfl_xor(p1, 2); p2 += __shfl_xor(p2, 2); p3 += __shfl_xor(p3, 2);
            p0 += __shfl_xor(p0, 4); p1 += __shfl_xor(p1, 4); p2 += __shfl_xor(p2, 4); p3 += __shfl_xor(p3, 4);
            p0 += __shfl_xor(p0, 8); p1 += __shfl_xor(p1, 8); p2 += __shfl_xor(p2, 8); p3 += __shfl_xor(p3, 8);
            float w0 = __expf(p0 * ATT_SCALE);
            float w1 = __expf(p1 * ATT_SCALE);
            float w2 = __expf(p2 * ATT_SCALE);
            float w3 = __expf(p3 * ATT_SCALE);
            denom += (w0 + w1) + (w2 + w3);
            o0 = fmaf(w0, b2f((u16)(v0 & 0xFFFF)), o0); o1 = fmaf(w0, b2f((u16)(v0 >> 16)), o1);
            o0 = fmaf(w1, b2f((u16)(v1 & 0xFFFF)), o0); o1 = fmaf(w1, b2f((u16)(v1 >> 16)), o1);
            o0 = fmaf(w2, b2f((u16)(v2 & 0xFFFF)), o0); o1 = fmaf(w2, b2f((u16)(v2 >> 16)), o1);
            o0 = fmaf(w3, b2f((u16)(v3 & 0xFFFF)), o0); o1 = fmaf(w3, b2f((u16)(v3 >> 16)), o1);
        }
        for (; j < m; ++j) {
            int s = __shfl(myidx, j);
            const u32 kk = *(const u32*)&Kb[(size_t)s * 128 + lane * 2];
            const u32 vv = *(const u32*)&Vb[(size_t)s * 128 + lane * 2];
            float p = q0 * b2f((u16)(kk & 0xFFFF)) + q1 * b2f((u16)(kk >> 16));
            p += __shfl_xor(p, 1); p += __shfl_xor(p, 2); p += __shfl_xor(p, 4); p += __shfl_xor(p, 8);
            float w = __expf(p * ATT_SCALE);
            denom += w;
            o0 = fmaf(w, b2f((u16)(vv & 0xFFFF)), o0);
            o1 = fmaf(w, b2f((u16)(vv >> 16)), o1);
        }
    }
    float inv = (deg > 0) ? (1.f / denom) : 0.f;
    u16 r0_ = f2b(o0 * inv), r1_ = f2b(o1 * inv);
    *(u32*)&hnew[(size_t)node * 128 + lane * 2] = (u32)r0_ | ((u32)r1_ << 16);
}

// ---------------------------------------------------------------------------
// Attn-out + residual + LN2:  h1 = h + hnew@Wo + bo (fp32); h2 = LN(h1) (bf16).
// Wave holds entire 16x128 output in accs -> in-register row LN.
// ---------------------------------------------------------------------------
__global__ __launch_bounds__(256) void k_attnout(
    const u16* __restrict__ hnew, const u16* __restrict__ Bo, const float* __restrict__ bo,
    const float* __restrict__ h, const float* __restrict__ g2, const float* __restrict__ be2,
    float* __restrict__ h1, u16* __restrict__ h2, int M)
{
    const int slab = blockIdx.x * 4 + (threadIdx.x >> 6);
    const int l = threadIdx.x & 63;
    const int r0 = slab * 16;
    if (r0 >= M) return;
    const int col = l & 15, hg = l >> 4;
    const u16* ar = hnew + (size_t)(r0 + col) * 128 + hg * 8;
    bf16x8 a0 = *(const bf16x8*)(ar);
    bf16x8 a1 = *(const bf16x8*)(ar + 32);
    bf16x8 a2 = *(const bf16x8*)(ar + 64);
    bf16x8 a3 = *(const bf16x8*)(ar + 96);
    f32x4 acc[8];
    #pragma unroll
    for (int t = 0; t < 8; ++t) {
        float bb = bo[t * 16 + col];
        f32x4 c = {bb, bb, bb, bb};
        const u16* bp = Bo + t * 2048 + l * 8;
        c = MFMA(a0, *(const bf16x8*)(bp),        c);
        c = MFMA(a1, *(const bf16x8*)(bp + 512),  c);
        c = MFMA(a2, *(const bf16x8*)(bp + 1024), c);
        c = MFMA(a3, *(const bf16x8*)(bp + 1536), c);
        acc[t] = c;
    }
    float s[4] = {0, 0, 0, 0}, s2[4] = {0, 0, 0, 0};
    #pragma unroll
    for (int t = 0; t < 8; ++t) {
        #pragma unroll
        for (int r = 0; r < 4; ++r) {
            float x = acc[t][r] + h[(size_t)(r0 + hg * 4 + r) * 128 + t * 16 + col];
            acc[t][r] = x;
            s[r] += x; s2[r] += x * x;
        }
    }
    float mean[4], rs[4];
    #pragma unroll
    for (int r = 0; r < 4; ++r) {
        float a = s[r], b = s2[r];
        a += __shfl_xor(a, 1); b += __shfl_xor(b, 1);
        a += __shfl_xor(a, 2); b += __shfl_xor(b, 2);
        a += __shfl_xor(a, 4); b += __shfl_xor(b, 4);
        a += __shfl_xor(a, 8); b += __shfl_xor(b, 8);
        mean[r] = a * (1.f / 128.f);
        float var = b * (1.f / 128.f) - mean[r] * mean[r];
        rs[r] = rsqrtf(var + EPS);
    }
    #pragma unroll
    for (int t = 0; t < 8; ++t) {
        float g  = g2[t * 16 + col];
        float be = be2[t * 16 + col];
        #pragma unroll
        for (int r = 0; r < 4; ++r) {
            size_t idx = (size_t)(r0 + hg * 4 + r) * 128 + t * 16 + col;
            float x = acc[t][r];
            h1[idx] = x;
            h2[idx] = f2b((x - mean[r]) * rs[r] * g + be);
        }
    }
}

// ---------------------------------------------------------------------------
// FFN1: t = relu(h2 @ W1 + b1)   (N=256, 16 tiles)
// ---------------------------------------------------------------------------
__global__ __launch_bounds__(256) void k_ffn1(
    const u16* __restrict__ h2, const u16* __restrict__ B1, const float* __restrict__ b1,
    u16* __restrict__ tb, int M)
{
    const int slab = blockIdx.x * 4 + (threadIdx.x >> 6);
    const int l = threadIdx.x & 63;
    const int r0 = slab * 16;
    if (r0 >= M) return;
    const int col = l & 15, hg = l >> 4;
    const u16* ar = h2 + (size_t)(r0 + col) * 128 + hg * 8;
    bf16x8 a0 = *(const bf16x8*)(ar);
    bf16x8 a1 = *(const bf16x8*)(ar + 32);
    bf16x8 a2 = *(const bf16x8*)(ar + 64);
    bf16x8 a3 = *(const bf16x8*)(ar + 96);
    #pragma unroll
    for (int t = 0; t < 16; ++t) {
        float bb = b1[t * 16 + col];
        f32x4 c = {bb, bb, bb, bb};
        const u16* bp = B1 + t * 2048 + l * 8;
        c = MFMA(a0, *(const bf16x8*)(bp),        c);
        c = MFMA(a1, *(const bf16x8*)(bp + 512),  c);
        c = MFMA(a2, *(const bf16x8*)(bp + 1024), c);
        c = MFMA(a3, *(const bf16x8*)(bp + 1536), c);
        #pragma unroll
        for (int r = 0; r < 4; ++r)
            tb[(size_t)(r0 + hg * 4 + r) * 256 + t * 16 + col] = f2b(fmaxf(c[r], 0.f));
    }
}

// ---------------------------------------------------------------------------
// FFN2: out = h1 + t @ W2 + b2   (K=256 -> 8 A-frags; fp32 out)
// ---------------------------------------------------------------------------
__global__ __launch_bounds__(256) void k_ffn2(
    const u16* __restrict__ tb, const u16* __restrict__ B2, const float* __restrict__ b2,
    const float* __restrict__ h1, float* __restrict__ out, int M)
{
    const int slab = blockIdx.x * 4 + (threadIdx.x >> 6);
    const int l = threadIdx.x & 63;
    const int r0 = slab * 16;
    if (r0 >= M) return;
    const int col = l & 15, hg = l >> 4;
    const u16* ar = tb + (size_t)(r0 + col) * 256 + hg * 8;
    bf16x8 a[8];
    #pragma unroll
    for (int i = 0; i < 8; ++i) a[i] = *(const bf16x8*)(ar + i * 32);
    #pragma unroll
    for (int t = 0; t < 8; ++t) {
        float bb = b2[t * 16 + col];
        f32x4 c = {bb, bb, bb, bb};
        const u16* bp = B2 + t * 4096 + l * 8;
        #pragma unroll
        for (int kc = 0; kc < 8; ++kc)
            c = MFMA(a[kc], *(const bf16x8*)(bp + kc * 512), c);
        #pragma unroll
        for (int r = 0; r < 4; ++r) {
            size_t idx = (size_t)(r0 + hg * 4 + r) * 128 + t * 16 + col;
            out[idx] = c[r] + h1[idx];
        }
    }
}

// ---------------------------------------------------------------------------
extern "C" void kernel_launch(void* const* d_in, const int* in_sizes, int n_in,
                              void* d_out, int out_size, void* d_ws, size_t ws_size,
                              hipStream_t stream)
{
    const float* h   = (const float*)d_in[0];
    const int*   src = (const int*)  d_in[1];
    const int*   dst = (const int*)  d_in[2];
    const float* Wq  = (const float*)d_in[3];
    const float* bq  = (const float*)d_in[4];
    const float* Wk  = (const float*)d_in[5];
    const float* bk  = (const float*)d_in[6];
    const float* Wv  = (const float*)d_in[7];
    const float* bv  = (const float*)d_in[8];
    const float* Wo  = (const float*)d_in[9];
    const float* bo  = (const float*)d_in[10];
    const float* W1  = (const float*)d_in[11];
    const float* b1  = (const float*)d_in[12];
    const float* W2  = (const float*)d_in[13];
    const float* b2  = (const float*)d_in[14];
    const float* g1  = (const float*)d_in[15];
    const float* be1 = (const float*)d_in[16];
    const float* g2  = (const float*)d_in[17];
    const float* be2 = (const float*)d_in[18];

    const int n = in_sizes[0] / HIDN;    // 100000
    const int e = in_sizes[1];           // 1600000
    float* out = (float*)d_out;

    // --- workspace layout (bytes) ---
    char* p = (char*)d_ws;
    int* csrc = (int*)p;               p += (size_t)e * 4;
    int* cnt  = (int*)p;               p += (size_t)n * 4;
    int* offs = (int*)p;               p += (size_t)n * 4;
    int* cur  = (int*)p;               p += (size_t)n * 4;
    int* bsum = (int*)p;               p += 1024;
    int* bofs = (int*)p;               p += 1024;
    u16* wpack = (u16*)p;              p += 131072 * 2;      // 256 KB packed weights
    const size_t NB = (size_t)n * HIDN * 2;                  // bf16 activation buffer
    u16* hn   = (u16*)p;               p += NB;              // LN1 out; later h2
    u16* Qb   = (u16*)p;               p += NB;              // later tb (with Kb)
    u16* Kb   = (u16*)p;               p += NB;
    u16* Vb   = (u16*)p;               p += NB;
    u16* hnew = (u16*)p;               p += NB;
    float* h1 = (float*)p;             p += (size_t)n * HIDN * 4;
    u16* h2 = hn;                      // alias: hn dead after k_qkv
    u16* tb = Qb;                      // alias: Qb+Kb dead after k_edge (needs 2*NB)

    u16* Wq_p = wpack;
    u16* Wk_p = wpack + 16384;
    u16* Wv_p = wpack + 32768;
    u16* Wo_p = wpack + 49152;
    u16* W1_p = wpack + 65536;
    u16* W2_p = wpack + 98304;

    const int nb = (n + 1023) / 1024;
    const int nslab = (n + 15) / 16;               // 16 rows per wave
    const int gemm_blocks = (nslab + 3) / 4;       // 4 waves per block

    hipMemsetAsync(cnt, 0, (size_t)n * sizeof(int), stream);

    k_count  <<<(e + 255) / 256, 256, 0, stream>>>(dst, cnt, e);
    k_scan1  <<<nb, 256, 0, stream>>>(cnt, offs, bsum, n);
    k_scan2  <<<1, 64, 0, stream>>>(bsum, bofs, nb);
    k_scan3  <<<(n + 255) / 256, 256, 0, stream>>>(bofs, offs, cur, n);
    k_scatter<<<(e + 255) / 256, 256, 0, stream>>>(src, dst, cur, csrc, e);

    k_pack_all<<<64, 256, 0, stream>>>(Wq, Wk, Wv, Wo, W1, W2, wpack);
    k_ln1    <<<(n + 3) / 4, 256, 0, stream>>>(h, g1, be1, hn, n);

    k_qkv    <<<gemm_blocks, 256, 0, stream>>>(hn, Wq_p, Wk_p, Wv_p, bq, bk, bv, Qb, Kb, Vb, n);

    k_edge   <<<(n + 3) / 4, 256, 0, stream>>>(Qb, Kb, Vb, offs, cnt, csrc, hnew, n);

    k_attnout<<<gemm_blocks, 256, 0, stream>>>(hnew, Wo_p, bo, h, g2, be2, h1, h2, n);

    k_ffn1   <<<gemm_blocks, 256, 0, stream>>>(h2, W1_p, b1, tb, n);

    k_ffn2   <<<gemm_blocks, 256, 0, stream>>>(tb, W2_p, b2, h1, out, n);
}

// Round 6
// 459.592 us; speedup vs baseline: 2.4032x; 1.2815x over previous
//
#include <hip/hip_runtime.h>
#include <math.h>

#define HIDN 128
#define EPS 1e-5f
#define ATT_SCALE 0.17677669529663687f   // 32^-0.5

typedef unsigned int  u32;
typedef unsigned short u16;
typedef __attribute__((ext_vector_type(8))) short bf16x8;   // 8 bf16 in 4 VGPRs
typedef __attribute__((ext_vector_type(4))) float f32x4;

__device__ __forceinline__ u16 f2b(float x) {           // fp32 -> bf16 RNE
    u32 u = __float_as_uint(x);
    u += 0x7FFFu + ((u >> 16) & 1u);
    return (u16)(u >> 16);
}
__device__ __forceinline__ float b2f(u16 x) { return __uint_as_float(((u32)x) << 16); }

#define MFMA(a, b, c) __builtin_amdgcn_mfma_f32_16x16x32_bf16((a), (b), (c), 0, 0, 0)

// ---------------------------------------------------------------------------
// LN1: hn = LN(h; g1, be1) as bf16.  One wave per row.
// ---------------------------------------------------------------------------
__global__ __launch_bounds__(256) void k_ln1(
    const float* __restrict__ h, const float* __restrict__ g, const float* __restrict__ b,
    u16* __restrict__ hn, int n)
{
    const int row = blockIdx.x * 4 + (threadIdx.x >> 6);
    const int lane = threadIdx.x & 63;
    if (row >= n) return;
    float2 v = *(const float2*)&h[(size_t)row * HIDN + lane * 2];
    float s = v.x + v.y, s2 = v.x * v.x + v.y * v.y;
    #pragma unroll
    for (int m = 1; m < 64; m <<= 1) { s += __shfl_xor(s, m); s2 += __shfl_xor(s2, m); }
    float mean = s * (1.f / 128.f);
    float var  = s2 * (1.f / 128.f) - mean * mean;
    float rs   = rsqrtf(var + EPS);
    float2 gv = *(const float2*)&g[lane * 2];
    float2 bv = *(const float2*)&b[lane * 2];
    u16 o0 = f2b((v.x - mean) * rs * gv.x + bv.x);
    u16 o1 = f2b((v.y - mean) * rs * gv.y + bv.y);
    *(u32*)&hn[(size_t)row * HIDN + lane * 2] = (u32)o0 | ((u32)o1 << 16);
}

// ---------------------------------------------------------------------------
// Pack all 6 weight matrices (fp32 row-major [K][N]) into MFMA B-fragment
// order, bf16.  Fragment fi = t*KC + c; lane l; elem j  ->  W[c*32 + (l>>4)*8 + j][t*16 + (l&15)]
// ---------------------------------------------------------------------------
__global__ __launch_bounds__(256) void k_pack_all(
    const float* __restrict__ Wq, const float* __restrict__ Wk, const float* __restrict__ Wv,
    const float* __restrict__ Wo, const float* __restrict__ W1, const float* __restrict__ W2,
    u16* __restrict__ out)
{
    int idx = blockIdx.x * 256 + threadIdx.x;
    const float* W; int K, N, base, local;
    if      (idx <  2048) { W = Wq; K = 128; N = 128; base = 0;     local = idx; }
    else if (idx <  4096) { W = Wk; K = 128; N = 128; base = 16384; local = idx - 2048; }
    else if (idx <  6144) { W = Wv; K = 128; N = 128; base = 32768; local = idx - 4096; }
    else if (idx <  8192) { W = Wo; K = 128; N = 128; base = 49152; local = idx - 6144; }
    else if (idx < 12288) { W = W1; K = 128; N = 256; base = 65536; local = idx - 8192; }
    else if (idx < 16384) { W = W2; K = 256; N = 128; base = 98304; local = idx - 12288; }
    else return;
    const int KC = K >> 5;
    const int l  = local & 63;
    const int tc = local >> 6;
    const int c  = tc % KC;
    const int t  = tc / KC;
    const int col = l & 15, hg = l >> 4;
    const int kbase = c * 32 + hg * 8;
    u16 v[8];
    #pragma unroll
    for (int j = 0; j < 8; ++j) v[j] = f2b(W[(size_t)(kbase + j) * N + t * 16 + col]);
    uint4 o;
    o.x = (u32)v[0] | ((u32)v[1] << 16);
    o.y = (u32)v[2] | ((u32)v[3] << 16);
    o.z = (u32)v[4] | ((u32)v[5] << 16);
    o.w = (u32)v[6] | ((u32)v[7] << 16);
    *(uint4*)&out[base + local * 8] = o;
}

// ---------------------------------------------------------------------------
// QKV: Q/K/V = hn @ W{q,k,v} + b.  One wave per 16 rows; A-frags in registers.
// ---------------------------------------------------------------------------
__global__ __launch_bounds__(256) void k_qkv(
    const u16* __restrict__ hn,
    const u16* __restrict__ Bq, const u16* __restrict__ Bk, const u16* __restrict__ Bv,
    const float* __restrict__ bq, const float* __restrict__ bk, const float* __restrict__ bv,
    u16* __restrict__ Q, u16* __restrict__ K, u16* __restrict__ V, int M)
{
    const int slab = blockIdx.x * 4 + (threadIdx.x >> 6);
    const int l = threadIdx.x & 63;
    const int r0 = slab * 16;
    if (r0 >= M) return;
    const int col = l & 15, hg = l >> 4;
    const u16* ar = hn + (size_t)(r0 + col) * 128 + hg * 8;
    bf16x8 a0 = *(const bf16x8*)(ar);
    bf16x8 a1 = *(const bf16x8*)(ar + 32);
    bf16x8 a2 = *(const bf16x8*)(ar + 64);
    bf16x8 a3 = *(const bf16x8*)(ar + 96);
    const u16*  Bs[3] = {Bq, Bk, Bv};
    const float* bs[3] = {bq, bk, bv};
    u16*        Os[3] = {Q, K, V};
    #pragma unroll
    for (int w = 0; w < 3; ++w) {
        const u16* Bp = Bs[w];
        const float* bias = bs[w];
        u16* O = Os[w];
        #pragma unroll
        for (int t = 0; t < 8; ++t) {
            float bb = bias[t * 16 + col];
            f32x4 c = {bb, bb, bb, bb};
            const u16* bp = Bp + t * 2048 + l * 8;
            c = MFMA(a0, *(const bf16x8*)(bp),        c);
            c = MFMA(a1, *(const bf16x8*)(bp + 512),  c);
            c = MFMA(a2, *(const bf16x8*)(bp + 1024), c);
            c = MFMA(a3, *(const bf16x8*)(bp + 1536), c);
            #pragma unroll
            for (int r = 0; r < 4; ++r)
                O[(size_t)(r0 + hg * 4 + r) * 128 + t * 16 + col] = f2b(c[r]);
        }
    }
}

// ---------------------------------------------------------------------------
// CSR build, two-level (bucket = 256 consecutive dst nodes).
// Kills the 100k-line random write frontier of the old per-node scatter:
// pass A scatters (src,dst) pairs to per-bucket regions with block-aggregated
// ranks (write frontier = NBUCK lines, amp ~1); pass B builds per-node
// cnt/offs and csrc inside one ~16KB bucket region per block (L2-local).
// ---------------------------------------------------------------------------
#define BSH 8                     // nodes per bucket = 256
#define CHUNK 4096                // edges per block in count/scatter passes

__global__ __launch_bounds__(256) void k_bcount(
    const int* __restrict__ dst, int* __restrict__ bcnt, int e)
{
    __shared__ int hist[512];
    const int tid = threadIdx.x;
    hist[tid] = 0; hist[tid + 256] = 0;
    __syncthreads();
    const int i0 = blockIdx.x * CHUNK;
    #pragma unroll
    for (int t = 0; t < CHUNK / 256; ++t) {
        int i = i0 + t * 256 + tid;
        if (i < e) atomicAdd(&hist[dst[i] >> BSH], 1);
    }
    __syncthreads();
    for (int j = tid; j < 512; j += 256) {
        int c = hist[j];
        if (c) atomicAdd(&bcnt[j], c);
    }
}

__global__ __launch_bounds__(512) void k_bscan(
    const int* __restrict__ bcnt, int* __restrict__ bbase, int* __restrict__ bcur, int nbuck)
{
    __shared__ int ts[512];
    const int tid = threadIdx.x;
    int v = (tid < nbuck) ? bcnt[tid] : 0;
    ts[tid] = v;
    __syncthreads();
    for (int off = 1; off < 512; off <<= 1) {
        int x = (tid >= off) ? ts[tid - off] : 0;
        __syncthreads();
        ts[tid] += x;
        __syncthreads();
    }
    int ex = ts[tid] - v;
    if (tid <= nbuck) bbase[tid] = ex;
    if (tid < nbuck)  bcur[tid]  = ex;
}

__global__ __launch_bounds__(256) void k_bscatter(
    const int* __restrict__ src, const int* __restrict__ dst,
    int* __restrict__ bcur, int2* __restrict__ ebuf, int e)
{
    __shared__ int hist[512];
    __shared__ int lbase[512];
    __shared__ int lrun[512];
    const int tid = threadIdx.x;
    hist[tid] = 0; hist[tid + 256] = 0;
    __syncthreads();
    const int i0 = blockIdx.x * CHUNK;
    #pragma unroll
    for (int t = 0; t < CHUNK / 256; ++t) {
        int i = i0 + t * 256 + tid;
        if (i < e) atomicAdd(&hist[dst[i] >> BSH], 1);
    }
    __syncthreads();
    for (int j = tid; j < 512; j += 256) {
        int c = hist[j];
        lrun[j] = 0;
        if (c) lbase[j] = atomicAdd(&bcur[j], c);
    }
    __syncthreads();
    #pragma unroll
    for (int t = 0; t < CHUNK / 256; ++t) {
        int i = i0 + t * 256 + tid;
        if (i < e) {
            int d = dst[i];
            int b = d >> BSH;
            int r = atomicAdd(&lrun[b], 1);
            ebuf[lbase[b] + r] = make_int2(src[i], d);
        }
    }
}

__global__ __launch_bounds__(256) void k_bbuild(
    const int2* __restrict__ ebuf, const int* __restrict__ bbase,
    int* __restrict__ cnt, int* __restrict__ offs, int* __restrict__ csrc, int n)
{
    __shared__ int ncnt[256];
    __shared__ int ts[256];
    __shared__ int nrun[256];
    const int tid = threadIdx.x;
    const int b = blockIdx.x;
    const int node0 = b << BSH;
    const int nn = min(256, n - node0);
    const int s = bbase[b];
    const int epb = bbase[b + 1] - s;

    ncnt[tid] = 0;
    __syncthreads();
    for (int i = tid; i < epb; i += 256)
        atomicAdd(&ncnt[ebuf[s + i].y & 255], 1);
    __syncthreads();
    int v = ncnt[tid];
    ts[tid] = v;
    __syncthreads();
    for (int off = 1; off < 256; off <<= 1) {
        int x = (tid >= off) ? ts[tid - off] : 0;
        __syncthreads();
        ts[tid] += x;
        __syncthreads();
    }
    int ex = ts[tid] - v;
    if (tid < nn) { cnt[node0 + tid] = v; offs[node0 + tid] = s + ex; }
    nrun[tid] = 0;
    __syncthreads();          // all reads of ncnt complete before repurposing
    ncnt[tid] = ex;           // ncnt now holds exclusive in-bucket offsets
    __syncthreads();
    for (int i = tid; i < epb; i += 256) {
        int2 p = ebuf[s + i];
        int d = p.y & 255;
        int r = atomicAdd(&nrun[d], 1);
        csrc[s + ncnt[d] + r] = p.x;
    }
}

// ---------------------------------------------------------------------------
// Edge attention: single pass, no max subtraction (scores are O(1) by
// construction -> exp is safe; softmax is shift-invariant so result identical).
// One wave per node; lane owns dims {2l, 2l+1}; head = lane>>4.
// ---------------------------------------------------------------------------
__global__ __launch_bounds__(256) void k_edge(
    const u16* __restrict__ Qb, const u16* __restrict__ Kb, const u16* __restrict__ Vb,
    const int* __restrict__ offs, const int* __restrict__ cnt, const int* __restrict__ csrc,
    u16* __restrict__ hnew, int n)
{
    const int wid  = threadIdx.x >> 6;
    const int lane = threadIdx.x & 63;
    const int node = blockIdx.x * 4 + wid;
    if (node >= n) return;
    const int start = offs[node];
    const int deg   = cnt[node];

    const u32 qu = *(const u32*)&Qb[(size_t)node * 128 + lane * 2];
    const float q0 = b2f((u16)(qu & 0xFFFF));
    const float q1 = b2f((u16)(qu >> 16));

    float denom = 0.f, o0 = 0.f, o1 = 0.f;

    for (int base = 0; base < deg; base += 64) {
        int m = deg - base; if (m > 64) m = 64;
        int myidx = 0;
        if (lane < m) myidx = csrc[start + base + lane];
        int j = 0;
        for (; j + 4 <= m; j += 4) {
            int s0 = __shfl(myidx, j + 0);
            int s1 = __shfl(myidx, j + 1);
            int s2 = __shfl(myidx, j + 2);
            int s3 = __shfl(myidx, j + 3);
            const u32 k0 = *(const u32*)&Kb[(size_t)s0 * 128 + lane * 2];
            const u32 k1 = *(const u32*)&Kb[(size_t)s1 * 128 + lane * 2];
            const u32 k2 = *(const u32*)&Kb[(size_t)s2 * 128 + lane * 2];
            const u32 k3 = *(const u32*)&Kb[(size_t)s3 * 128 + lane * 2];
            const u32 v0 = *(const u32*)&Vb[(size_t)s0 * 128 + lane * 2];
            const u32 v1 = *(const u32*)&Vb[(size_t)s1 * 128 + lane * 2];
            const u32 v2 = *(const u32*)&Vb[(size_t)s2 * 128 + lane * 2];
            const u32 v3 = *(const u32*)&Vb[(size_t)s3 * 128 + lane * 2];
            float p0 = q0 * b2f((u16)(k0 & 0xFFFF)) + q1 * b2f((u16)(k0 >> 16));
            float p1 = q0 * b2f((u16)(k1 & 0xFFFF)) + q1 * b2f((u16)(k1 >> 16));
            float p2 = q0 * b2f((u16)(k2 & 0xFFFF)) + q1 * b2f((u16)(k2 >> 16));
            float p3 = q0 * b2f((u16)(k3 & 0xFFFF)) + q1 * b2f((u16)(k3 >> 16));
            p0 += __shfl_xor(p0, 1); p1 += __shfl_xor(p1, 1); p2 += __shfl_xor(p2, 1); p3 += __shfl_xor(p3, 1);
            p0 += __shfl_xor(p0, 2); p1 += __shfl_xor(p1, 2); p2 += __shfl_xor(p2, 2); p3 += __shfl_xor(p3, 2);
            p0 += __shfl_xor(p0, 4); p1 += __shfl_xor(p1, 4); p2 += __shfl_xor(p2, 4); p3 += __shfl_xor(p3, 4);
            p0 += __shfl_xor(p0, 8); p1 += __shfl_xor(p1, 8); p2 += __shfl_xor(p2, 8); p3 += __shfl_xor(p3, 8);
            float w0 = __expf(p0 * ATT_SCALE);
            float w1 = __expf(p1 * ATT_SCALE);
            float w2 = __expf(p2 * ATT_SCALE);
            float w3 = __expf(p3 * ATT_SCALE);
            denom += (w0 + w1) + (w2 + w3);
            o0 = fmaf(w0, b2f((u16)(v0 & 0xFFFF)), o0); o1 = fmaf(w0, b2f((u16)(v0 >> 16)), o1);
            o0 = fmaf(w1, b2f((u16)(v1 & 0xFFFF)), o0); o1 = fmaf(w1, b2f((u16)(v1 >> 16)), o1);
            o0 = fmaf(w2, b2f((u16)(v2 & 0xFFFF)), o0); o1 = fmaf(w2, b2f((u16)(v2 >> 16)), o1);
            o0 = fmaf(w3, b2f((u16)(v3 & 0xFFFF)), o0); o1 = fmaf(w3, b2f((u16)(v3 >> 16)), o1);
        }
        for (; j < m; ++j) {
            int s = __shfl(myidx, j);
            const u32 kk = *(const u32*)&Kb[(size_t)s * 128 + lane * 2];
            const u32 vv = *(const u32*)&Vb[(size_t)s * 128 + lane * 2];
            float p = q0 * b2f((u16)(kk & 0xFFFF)) + q1 * b2f((u16)(kk >> 16));
            p += __shfl_xor(p, 1); p += __shfl_xor(p, 2); p += __shfl_xor(p, 4); p += __shfl_xor(p, 8);
            float w = __expf(p * ATT_SCALE);
            denom += w;
            o0 = fmaf(w, b2f((u16)(vv & 0xFFFF)), o0);
            o1 = fmaf(w, b2f((u16)(vv >> 16)), o1);
        }
    }
    float inv = (deg > 0) ? (1.f / denom) : 0.f;
    u16 r0_ = f2b(o0 * inv), r1_ = f2b(o1 * inv);
    *(u32*)&hnew[(size_t)node * 128 + lane * 2] = (u32)r0_ | ((u32)r1_ << 16);
}

// ---------------------------------------------------------------------------
// Attn-out + residual + LN2:  h1 = h + hnew@Wo + bo (fp32); h2 = LN(h1) (bf16).
// ---------------------------------------------------------------------------
__global__ __launch_bounds__(256) void k_attnout(
    const u16* __restrict__ hnew, const u16* __restrict__ Bo, const float* __restrict__ bo,
    const float* __restrict__ h, const float* __restrict__ g2, const float* __restrict__ be2,
    float* __restrict__ h1, u16* __restrict__ h2, int M)
{
    const int slab = blockIdx.x * 4 + (threadIdx.x >> 6);
    const int l = threadIdx.x & 63;
    const int r0 = slab * 16;
    if (r0 >= M) return;
    const int col = l & 15, hg = l >> 4;
    const u16* ar = hnew + (size_t)(r0 + col) * 128 + hg * 8;
    bf16x8 a0 = *(const bf16x8*)(ar);
    bf16x8 a1 = *(const bf16x8*)(ar + 32);
    bf16x8 a2 = *(const bf16x8*)(ar + 64);
    bf16x8 a3 = *(const bf16x8*)(ar + 96);
    f32x4 acc[8];
    #pragma unroll
    for (int t = 0; t < 8; ++t) {
        float bb = bo[t * 16 + col];
        f32x4 c = {bb, bb, bb, bb};
        const u16* bp = Bo + t * 2048 + l * 8;
        c = MFMA(a0, *(const bf16x8*)(bp),        c);
        c = MFMA(a1, *(const bf16x8*)(bp + 512),  c);
        c = MFMA(a2, *(const bf16x8*)(bp + 1024), c);
        c = MFMA(a3, *(const bf16x8*)(bp + 1536), c);
        acc[t] = c;
    }
    float s[4] = {0, 0, 0, 0}, s2[4] = {0, 0, 0, 0};
    #pragma unroll
    for (int t = 0; t < 8; ++t) {
        #pragma unroll
        for (int r = 0; r < 4; ++r) {
            float x = acc[t][r] + h[(size_t)(r0 + hg * 4 + r) * 128 + t * 16 + col];
            acc[t][r] = x;
            s[r] += x; s2[r] += x * x;
        }
    }
    float mean[4], rs[4];
    #pragma unroll
    for (int r = 0; r < 4; ++r) {
        float a = s[r], b = s2[r];
        a += __shfl_xor(a, 1); b += __shfl_xor(b, 1);
        a += __shfl_xor(a, 2); b += __shfl_xor(b, 2);
        a += __shfl_xor(a, 4); b += __shfl_xor(b, 4);
        a += __shfl_xor(a, 8); b += __shfl_xor(b, 8);
        mean[r] = a * (1.f / 128.f);
        float var = b * (1.f / 128.f) - mean[r] * mean[r];
        rs[r] = rsqrtf(var + EPS);
    }
    #pragma unroll
    for (int t = 0; t < 8; ++t) {
        float g  = g2[t * 16 + col];
        float be = be2[t * 16 + col];
        #pragma unroll
        for (int r = 0; r < 4; ++r) {
            size_t idx = (size_t)(r0 + hg * 4 + r) * 128 + t * 16 + col;
            float x = acc[t][r];
            h1[idx] = x;
            h2[idx] = f2b((x - mean[r]) * rs[r] * g + be);
        }
    }
}

// ---------------------------------------------------------------------------
// FFN1: t = relu(h2 @ W1 + b1)   (N=256, 16 tiles)
// ---------------------------------------------------------------------------
__global__ __launch_bounds__(256) void k_ffn1(
    const u16* __restrict__ h2, const u16* __restrict__ B1, const float* __restrict__ b1,
    u16* __restrict__ tb, int M)
{
    const int slab = blockIdx.x * 4 + (threadIdx.x >> 6);
    const int l = threadIdx.x & 63;
    const int r0 = slab * 16;
    if (r0 >= M) return;
    const int col = l & 15, hg = l >> 4;
    const u16* ar = h2 + (size_t)(r0 + col) * 128 + hg * 8;
    bf16x8 a0 = *(const bf16x8*)(ar);
    bf16x8 a1 = *(const bf16x8*)(ar + 32);
    bf16x8 a2 = *(const bf16x8*)(ar + 64);
    bf16x8 a3 = *(const bf16x8*)(ar + 96);
    #pragma unroll
    for (int t = 0; t < 16; ++t) {
        float bb = b1[t * 16 + col];
        f32x4 c = {bb, bb, bb, bb};
        const u16* bp = B1 + t * 2048 + l * 8;
        c = MFMA(a0, *(const bf16x8*)(bp),        c);
        c = MFMA(a1, *(const bf16x8*)(bp + 512),  c);
        c = MFMA(a2, *(const bf16x8*)(bp + 1024), c);
        c = MFMA(a3, *(const bf16x8*)(bp + 1536), c);
        #pragma unroll
        for (int r = 0; r < 4; ++r)
            tb[(size_t)(r0 + hg * 4 + r) * 256 + t * 16 + col] = f2b(fmaxf(c[r], 0.f));
    }
}

// ---------------------------------------------------------------------------
// FFN2: out = h1 + t @ W2 + b2   (K=256 -> 8 A-frags; fp32 out)
// ---------------------------------------------------------------------------
__global__ __launch_bounds__(256) void k_ffn2(
    const u16* __restrict__ tb, const u16* __restrict__ B2, const float* __restrict__ b2,
    const float* __restrict__ h1, float* __restrict__ out, int M)
{
    const int slab = blockIdx.x * 4 + (threadIdx.x >> 6);
    const int l = threadIdx.x & 63;
    const int r0 = slab * 16;
    if (r0 >= M) return;
    const int col = l & 15, hg = l >> 4;
    const u16* ar = tb + (size_t)(r0 + col) * 256 + hg * 8;
    bf16x8 a[8];
    #pragma unroll
    for (int i = 0; i < 8; ++i) a[i] = *(const bf16x8*)(ar + i * 32);
    #pragma unroll
    for (int t = 0; t < 8; ++t) {
        float bb = b2[t * 16 + col];
        f32x4 c = {bb, bb, bb, bb};
        const u16* bp = B2 + t * 4096 + l * 8;
        #pragma unroll
        for (int kc = 0; kc < 8; ++kc)
            c = MFMA(a[kc], *(const bf16x8*)(bp + kc * 512), c);
        #pragma unroll
        for (int r = 0; r < 4; ++r) {
            size_t idx = (size_t)(r0 + hg * 4 + r) * 128 + t * 16 + col;
            out[idx] = c[r] + h1[idx];
        }
    }
}

// ---------------------------------------------------------------------------
extern "C" void kernel_launch(void* const* d_in, const int* in_sizes, int n_in,
                              void* d_out, int out_size, void* d_ws, size_t ws_size,
                              hipStream_t stream)
{
    const float* h   = (const float*)d_in[0];
    const int*   src = (const int*)  d_in[1];
    const int*   dst = (const int*)  d_in[2];
    const float* Wq  = (const float*)d_in[3];
    const float* bq  = (const float*)d_in[4];
    const float* Wk  = (const float*)d_in[5];
    const float* bk  = (const float*)d_in[6];
    const float* Wv  = (const float*)d_in[7];
    const float* bv  = (const float*)d_in[8];
    const float* Wo  = (const float*)d_in[9];
    const float* bo  = (const float*)d_in[10];
    const float* W1  = (const float*)d_in[11];
    const float* b1  = (const float*)d_in[12];
    const float* W2  = (const float*)d_in[13];
    const float* b2  = (const float*)d_in[14];
    const float* g1  = (const float*)d_in[15];
    const float* be1 = (const float*)d_in[16];
    const float* g2  = (const float*)d_in[17];
    const float* be2 = (const float*)d_in[18];

    const int n = in_sizes[0] / HIDN;    // 100000
    const int e = in_sizes[1];           // 1600000
    float* out = (float*)d_out;

    const int nbuck = (n + 255) >> BSH;  // 391

    // --- workspace layout (bytes; every chunk a multiple of 8) ---
    char* p = (char*)d_ws;
    int* csrc  = (int*)p;              p += (size_t)e * 4;
    int* cnt   = (int*)p;              p += (size_t)n * 4;
    int* offs  = (int*)p;              p += (size_t)n * 4;
    int* bcnt  = (int*)p;              p += 512 * 4;
    int* bbase = (int*)p;              p += 512 * 4;
    int* bcur  = (int*)p;              p += 512 * 4;
    u16* wpack = (u16*)p;              p += 131072 * 2;      // 256 KB packed weights
    const size_t NB = (size_t)n * HIDN * 2;                  // bf16 activation buffer
    u16* hn   = (u16*)p;               p += NB;              // LN1 out; later h2
    u16* Qb   = (u16*)p;               p += NB;              // later tb (with Kb)
    u16* Kb   = (u16*)p;               p += NB;
    u16* Vb   = (u16*)p;               p += NB;
    u16* hnew = (u16*)p;               p += NB;
    float* h1 = (float*)p;             p += (size_t)n * HIDN * 4;
    u16* h2 = hn;                      // alias: hn dead after k_qkv
    u16* tb = Qb;                      // alias: Qb+Kb dead after k_edge (needs 2*NB)
    int2* ebuf = (int2*)h1;            // alias: ebuf dead before k_attnout writes h1

    u16* Wq_p = wpack;
    u16* Wk_p = wpack + 16384;
    u16* Wv_p = wpack + 32768;
    u16* Wo_p = wpack + 49152;
    u16* W1_p = wpack + 65536;
    u16* W2_p = wpack + 98304;

    const int nslab = (n + 15) / 16;               // 16 rows per wave
    const int gemm_blocks = (nslab + 3) / 4;       // 4 waves per block
    const int echunks = (e + CHUNK - 1) / CHUNK;   // 391

    hipMemsetAsync(bcnt, 0, 512 * sizeof(int), stream);

    k_bcount  <<<echunks, 256, 0, stream>>>(dst, bcnt, e);
    k_bscan   <<<1, 512, 0, stream>>>(bcnt, bbase, bcur, nbuck);
    k_bscatter<<<echunks, 256, 0, stream>>>(src, dst, bcur, ebuf, e);
    k_bbuild  <<<nbuck, 256, 0, stream>>>(ebuf, bbase, cnt, offs, csrc, n);

    k_pack_all<<<64, 256, 0, stream>>>(Wq, Wk, Wv, Wo, W1, W2, wpack);
    k_ln1    <<<(n + 3) / 4, 256, 0, stream>>>(h, g1, be1, hn, n);

    k_qkv    <<<gemm_blocks, 256, 0, stream>>>(hn, Wq_p, Wk_p, Wv_p, bq, bk, bv, Qb, Kb, Vb, n);

    k_edge   <<<(n + 3) / 4, 256, 0, stream>>>(Qb, Kb, Vb, offs, cnt, csrc, hnew, n);

    k_attnout<<<gemm_blocks, 256, 0, stream>>>(hnew, Wo_p, bo, h, g2, be2, h1, h2, n);

    k_ffn1   <<<gemm_blocks, 256, 0, stream>>>(h2, W1_p, b1, tb, n);

    k_ffn2   <<<gemm_blocks, 256, 0, stream>>>(tb, W2_p, b2, h1, out, n);
}